// Round 15
// baseline (9045.673 us; speedup 1.0000x reference)
//
#include <hip/hip_runtime.h>
#include <stdint.h>

#define BSZ  128
#define TLEN 8192
#define MDIM 64
#define SDIM 512
#define NEG_BIG (-1e30f)
#define QA   127   // signed-i8-safe quantization range (bytes in [0,127])

typedef int i32x4 __attribute__((ext_vector_type(4)));

// Wave-wide (64-lane) max via DPP, no LDS. Verified R3-R14 (absmax 0).
__device__ __forceinline__ float wave_max_f32(float x) {
  int v = __builtin_bit_cast(int, x);
#define DPP_STEP(ctrl)                                                        \
  {                                                                           \
    int o = __builtin_amdgcn_update_dpp(v, v, ctrl, 0xf, 0xf, false);         \
    v = __builtin_bit_cast(int, fmaxf(__builtin_bit_cast(float, v),           \
                                      __builtin_bit_cast(float, o)));         \
  }
  DPP_STEP(0x111)  // row_shr:1
  DPP_STEP(0x112)  // row_shr:2
  DPP_STEP(0x114)  // row_shr:4
  DPP_STEP(0x118)  // row_shr:8
  DPP_STEP(0x142)  // row_bcast15
  DPP_STEP(0x143)  // row_bcast31 -> lane63 has max(0..63)
#undef DPP_STEP
  return __builtin_bit_cast(float, __builtin_amdgcn_readlane(v, 63));
}

// Extract symbol index from one-hot rows: sym[b,t] = argmax_m x[b,t,m]
__global__ void sym_kernel(const float* __restrict__ x, uint8_t* __restrict__ sym) {
  int i = blockIdx.x * blockDim.x + threadIdx.x;  // flat (b,t)
  const float4* p = (const float4*)(x + (size_t)i * MDIM);
  int idx = 0;
  #pragma unroll
  for (int j = 0; j < 16; ++j) {
    float4 v = p[j];
    if (v.x > 0.5f) idx = 4*j + 0;
    if (v.y > 0.5f) idx = 4*j + 1;
    if (v.z > 0.5f) idx = 4*j + 2;
    if (v.w > 0.5f) idx = 4*j + 3;
  }
  sym[i] = (uint8_t)idx;
}

// Per-column max of A (quantization scale). One 64-thread block per column.
__global__ void colmax_kernel(const float* __restrict__ A, float* __restrict__ cmax) {
  int c = blockIdx.x, l = threadIdx.x;
  float m = 0.f;
  for (int r = l; r < SDIM; r += 64) m = fmaxf(m, A[(size_t)r * SDIM + c]);
  #pragma unroll
  for (int off = 32; off; off >>= 1) m = fmaxf(m, __shfl_xor(m, off));
  if (l == 0) cmax[c] = m;
}

// Pack A column-major as u8 row-quads: Aq[c*128 + j] = A[4j..4j+3][c] scaled
__global__ void pack_kernel(const float* __restrict__ A, const float* __restrict__ cmax,
                            unsigned* __restrict__ Aq) {
  int id = blockIdx.x * 256 + threadIdx.x;   // 512*128 = 65536 ids
  int c = id >> 7, j = id & 127;
  float s = (float)QA / cmax[c];
  unsigned q = 0;
  #pragma unroll
  for (int bb = 0; bb < 4; ++bb) {
    float v = A[(size_t)(4 * j + bb) * SDIM + c];
    int qi = (int)(v * s + 0.5f);
    if (qi > QA) qi = QA;
    q |= (unsigned)qi << (8 * bb);
  }
  Aq[c * 128 + j] = q;
}

// Linear-space scaled forward (R12 math). ONE barrier per step:
// each wave quantizes with its OWN max (pre-barrier, no global reduce on
// the critical path) and posts one exponent byte; after the barrier the
// p-bytes are brought to the common (max) scale by a uniform per-byte
// rounded shift -- all 16 bytes of a P-register come from one source wave,
// so the shift amount is register-uniform (2 VALU ops per register).
// Waves >=7 bits below the max contribute exactly-zero bytes: their
// rescale+MFMAs are skipped via a scalar uniform branch (exact identity).
__global__
#if __has_attribute(amdgpu_waves_per_eu)
__attribute__((amdgpu_waves_per_eu(2, 2)))
#endif
__launch_bounds__(512) void hmm_fwd(
    const unsigned* __restrict__ Aq, const float* __restrict__ cmax,
    const float* __restrict__ Bm, const uint8_t* __restrict__ sym,
    float* __restrict__ out) {
  const int b  = blockIdx.x;
  const int t  = threadIdx.x;        // == state owned
  const int wv = t >> 6;             // wave 0..7 -> cols 64wv..64wv+63
  const int ln = t & 63;
  const int pg = ln >> 4;            // K-subgroup / col-tile id

  __shared__ __align__(16) uint8_t p8[2][SDIM];  // quantized p, dbuf
  __shared__ __align__(8)  uint8_t e8[2][8];     // per-wave exponent bytes
  __shared__ float red2[8];

  // ---- B-operand tiles: 4 col-tiles x 8 K-tiles, 32 uint4 (AGPR-parked) ----
  const uint4* aq4 = (const uint4*)Aq;
  const int cb = (wv << 6) + (ln & 15);          // this lane's base col
#define LDB(TT, KT) aq4[(size_t)(cb + 16 * TT) * 32 + KT * 4 + pg]
  uint4 B00=LDB(0,0),B01=LDB(0,1),B02=LDB(0,2),B03=LDB(0,3),
        B04=LDB(0,4),B05=LDB(0,5),B06=LDB(0,6),B07=LDB(0,7);
  uint4 B10=LDB(1,0),B11=LDB(1,1),B12=LDB(1,2),B13=LDB(1,3),
        B14=LDB(1,4),B15=LDB(1,5),B16=LDB(1,6),B17=LDB(1,7);
  uint4 B20=LDB(2,0),B21=LDB(2,1),B22=LDB(2,2),B23=LDB(2,3),
        B24=LDB(2,4),B25=LDB(2,5),B26=LDB(2,6),B27=LDB(2,7);
  uint4 B30=LDB(3,0),B31=LDB(3,1),B32=LDB(3,2),B33=LDB(3,3),
        B34=LDB(3,4),B35=LDB(3,5),B36=LDB(3,6),B37=LDB(3,7);
#undef LDB

  const float cscale = cmax[t] * (1.0f / ((float)QA * (float)QA));
  const uint8_t* symb = sym + (size_t)b * TLEN;

  // ---- init: v0 = exp(alpha0) = (B[s0,0]+eps) for t==0, else 0 ----
  int s0 = symb[0];
  float vReg = (t == 0) ? (Bm[s0 * SDIM + t] + 1e-16f) : 0.f;
  int   E_acc = 0;
  int   symNext = symb[1];
  float Ecur = Bm[symNext * SDIM + t] + 1e-16f;   // E_1 + eps
  symNext = symb[2];

  for (int step = 1; step < TLEN; ++step) {
    const int par = step & 1;

    // ---- pre-barrier: quantize with OWN wave scale ----
    float m_w = wave_max_f32(vReg);
    unsigned ebw = (__builtin_bit_cast(unsigned, m_w) >> 23) & 255u;
    float sqQ = __builtin_bit_cast(float, (253u - ebw) << 23) * (float)QA;
    p8[par][t] = (uint8_t)(unsigned)fmaf(vReg, sqQ, 0.5f);
    if (ln == 0) e8[par][wv] = (uint8_t)ebw;
    __syncthreads();                  // THE barrier (p8 + e8 ready)

    // prefetches (hide under MFMA phase)
    float Enxt  = Bm[symNext * SDIM + t] + 1e-16f;
    int   symNN = (int)symb[(step + 2 <= TLEN - 1) ? step + 2 : TLEN - 1];

    // ---- exponents -> scalar domain (uniform branches) ----
    uint2 ev = *(const uint2*)&e8[par][0];
    unsigned sx = (unsigned)__builtin_amdgcn_readfirstlane((int)ev.x);
    unsigned sy = (unsigned)__builtin_amdgcn_readfirstlane((int)ev.y);
    unsigned ek0 = sx & 255u, ek1 = (sx >> 8) & 255u,
             ek2 = (sx >> 16) & 255u, ek3 = sx >> 24;
    unsigned ek4 = sy & 255u, ek5 = (sy >> 8) & 255u,
             ek6 = (sy >> 16) & 255u, ek7 = sy >> 24;
    unsigned Ea = ek0 > ek1 ? ek0 : ek1, Eb = ek2 > ek3 ? ek2 : ek3;
    unsigned Ec = ek4 > ek5 ? ek4 : ek5, Ed = ek6 > ek7 ? ek6 : ek7;
    unsigned Ee = Ea > Eb ? Ea : Eb,     Ef = Ec > Ed ? Ec : Ed;
    unsigned E  = Ee > Ef ? Ee : Ef;

    // ---- P loads (all 8, pipelined) ----
    const uint4* pq = (const uint4*)p8[par];
    uint4 P0 = pq[0*4+pg], P1 = pq[1*4+pg], P2 = pq[2*4+pg], P3 = pq[3*4+pg];
    uint4 P4 = pq[4*4+pg], P5 = pq[5*4+pg], P6 = pq[6*4+pg], P7 = pq[7*4+pg];

    i32x4 l0={0,0,0,0}, l1={0,0,0,0}, l2={0,0,0,0}, l3={0,0,0,0};
    i32x4 h0={0,0,0,0}, h1={0,0,0,0}, h2={0,0,0,0}, h3={0,0,0,0};
#define MF(P, B, C) C = __builtin_amdgcn_mfma_i32_16x16x64_i8(                \
        __builtin_bit_cast(i32x4, P), __builtin_bit_cast(i32x4, B), C, 0, 0, 0)
    // Rescale to common scale E (rounded byte shift), skip zero waves.
#define KT_BLOCK(PK, EK, C0, C1, C2, C3, BT0, BT1, BT2, BT3)                  \
    {                                                                         \
      unsigned d = E - (EK);                                                  \
      if (d < 7u) {                                                           \
        unsigned rb = d ? 0x01010101u * (1u << (d - 1)) : 0u;                 \
        unsigned mk = (0xFFu >> d) * 0x01010101u;                             \
        PK.x = ((PK.x + rb) >> d) & mk; PK.y = ((PK.y + rb) >> d) & mk;       \
        PK.z = ((PK.z + rb) >> d) & mk; PK.w = ((PK.w + rb) >> d) & mk;       \
        MF(PK, BT0, C0); MF(PK, BT1, C1); MF(PK, BT2, C2); MF(PK, BT3, C3);   \
      }                                                                       \
    }
    KT_BLOCK(P0, ek0, l0, l1, l2, l3, B00, B10, B20, B30)
    KT_BLOCK(P1, ek1, l0, l1, l2, l3, B01, B11, B21, B31)
    KT_BLOCK(P2, ek2, l0, l1, l2, l3, B02, B12, B22, B32)
    KT_BLOCK(P3, ek3, l0, l1, l2, l3, B03, B13, B23, B33)
    KT_BLOCK(P4, ek4, h0, h1, h2, h3, B04, B14, B24, B34)
    KT_BLOCK(P5, ek5, h0, h1, h2, h3, B05, B15, B25, B35)
    KT_BLOCK(P6, ek6, h0, h1, h2, h3, B06, B16, B26, B36)
    KT_BLOCK(P7, ek7, h0, h1, h2, h3, B07, B17, B27, B37)
#undef KT_BLOCK
#undef MF

    // ---- extract own-column result: tile pg, any row (all rows equal) ----
    int rlo = (pg & 2) ? ((pg & 1) ? l3.x : l2.x)
                       : ((pg & 1) ? l1.x : l0.x);
    int rhi = (pg & 2) ? ((pg & 1) ? h3.x : h2.x)
                       : ((pg & 1) ? h1.x : h0.x);
    int rv = rlo + rhi;

    // ---- v-update (exact ref math in linear space, E_acc ledger) ----
    vReg  = fmaf((float)rv, cscale, 1e-16f) * Ecur;
    E_acc += (int)E - 126;            // scale used was 2^(E-126)
    Ecur  = Enxt;
    symNext = symNN;
  }

  // ---- outputs: alpha_T = log(v) + E_acc*ln2, then loglik ----
  float alphaReg = __logf(vReg) + (float)E_acc * 0.6931471805599453f;
  out[(size_t)b * SDIM + t] = alphaReg;

  float mx = wave_max_f32(alphaReg);
  if (ln == 0) red2[wv] = mx;
  __syncthreads();
  float mf = fmaxf(fmaxf(fmaxf(red2[0], red2[1]), fmaxf(red2[2], red2[3])),
                   fmaxf(fmaxf(red2[4], red2[5]), fmaxf(red2[6], red2[7])));

  float se = __expf(alphaReg - mf);
  #pragma unroll
  for (int off = 32; off; off >>= 1) se += __shfl_xor(se, off);
  __syncthreads();                    // red2 reads done before rewrite
  if (ln == 0) red2[wv] = se;
  __syncthreads();
  if (t == 0) {
    float tot = 0.f;
    #pragma unroll
    for (int k = 0; k < 8; ++k) tot += red2[k];
    out[(size_t)BSZ * SDIM + b] = __logf(tot + SDIM * 1e-16f) + mf;
  }
}

extern "C" void kernel_launch(void* const* d_in, const int* in_sizes, int n_in,
                              void* d_out, int out_size, void* d_ws, size_t ws_size,
                              hipStream_t stream) {
  const float* x  = (const float*)d_in[0];
  const float* A  = (const float*)d_in[1];
  const float* Bm = (const float*)d_in[2];
  float* out = (float*)d_out;

  uint8_t*  sym  = (uint8_t*)d_ws;                                  // 1 MB
  unsigned* Aq   = (unsigned*)((char*)d_ws + (1 << 20));            // 256 KB
  float*    cmax = (float*)((char*)d_ws + (1 << 20) + (256 << 10)); // 2 KB

  sym_kernel<<<(BSZ * TLEN) / 256, 256, 0, stream>>>(x, sym);
  colmax_kernel<<<SDIM, 64, 0, stream>>>(A, cmax);
  pack_kernel<<<(SDIM * 128) / 256, 256, 0, stream>>>(A, cmax, Aq);
  hmm_fwd<<<BSZ, 512, 0, stream>>>(Aq, cmax, Bm, sym, out);
}